// Round 6
// baseline (202.345 us; speedup 1.0000x reference)
//
#include <hip/hip_runtime.h>
#include <hip/hip_bf16.h>
#include <stdint.h>

#define T_TOK 8192
#define DIM   1024
#define NEXP  16
#define ESZ   256
#define TOPK  4
#define BM    128
#define BK    64
#define NPAIR (T_TOK*TOPK)                 // 32768
#define NBLK  128                          // hist/scatter blocks (256 pairs each)
#define MAXROWS (T_TOK*TOPK + NEXP*BM)     // 34816 padded assignment rows
#define MAXTILES (T_TOK*TOPK/BM + NEXP)    // 272  (= 8 XCD * 34)

typedef __hip_bfloat16 bf16;
typedef short bf16x8 __attribute__((ext_vector_type(8)));
typedef float f32x4 __attribute__((ext_vector_type(4)));

__device__ __forceinline__ unsigned short f2bu(float f){
  __hip_bfloat16 b = __float2bfloat16(f);
  return *reinterpret_cast<unsigned short*>(&b);
}
__device__ __forceinline__ float bu2f(unsigned short u){
  __hip_bfloat16 b = *reinterpret_cast<__hip_bfloat16*>(&u);
  return __bfloat162float(b);
}

__device__ __forceinline__ void gload16(const void* g, void* l){
  __builtin_amdgcn_global_load_lds((const __attribute__((address_space(1))) void*)g,
                                   (__attribute__((address_space(3))) void*)l, 16, 0, 0);
}

// ---------------- gating: logits -> sigmoid -> top4, fused x->bf16 ----------
__global__ __launch_bounds__(256) void k_gate(const float* __restrict__ x,
    const float* __restrict__ wg, bf16* __restrict__ xb,
    int* __restrict__ sel_idx, float* __restrict__ sel_gate)
{
  const int wave = threadIdx.x >> 6, lane = threadIdx.x & 63;
  const int t = blockIdx.x*4 + wave;
  const float* xr = x + (size_t)t*DIM;
  float4 xv[4];
#pragma unroll
  for (int c=0;c<4;c++) xv[c] = *(const float4*)(xr + c*256 + lane*4);
#pragma unroll
  for (int c=0;c<4;c++){
    ushort4 o; o.x=f2bu(xv[c].x); o.y=f2bu(xv[c].y); o.z=f2bu(xv[c].z); o.w=f2bu(xv[c].w);
    *(ushort4*)((unsigned short*)xb + (size_t)t*DIM + c*256 + lane*4) = o;
  }
  float sg[NEXP];
#pragma unroll
  for (int e=0;e<NEXP;e++){
    const float* wr = wg + e*DIM;
    float p = 0.f;
#pragma unroll
    for (int c=0;c<4;c++){
      float4 w = *(const float4*)(wr + c*256 + lane*4);
      p += xv[c].x*w.x + xv[c].y*w.y + xv[c].z*w.z + xv[c].w*w.w;
    }
#pragma unroll
    for (int s=1;s<64;s<<=1) p += __shfl_xor(p, s);
    sg[e] = 1.f/(1.f + expf(-p));
  }
  if (lane==0){
    unsigned chosen = 0;
#pragma unroll
    for (int k=0;k<TOPK;k++){
      float best=-1.f; int bi=0;
#pragma unroll
      for (int e=0;e<NEXP;e++){
        float v = ((chosen>>e)&1u) ? -2.f : sg[e];
        if (v>best){best=v;bi=e;}
      }
      chosen |= 1u<<bi;
      sel_idx[t*TOPK+k]=bi; sel_gate[t*TOPK+k]=best;
    }
  }
}

// ------- merged fp32->bf16 transposes: keys (z<16) and values (z>=16) -------
__global__ __launch_bounds__(256) void k_transpose2(const float* __restrict__ keys,
    const float* __restrict__ values, bf16* __restrict__ kT, bf16* __restrict__ vT)
{
  __shared__ float tile[32][33];
  const int which = blockIdx.y >> 4, e = blockIdx.y & 15;
  const int R = which ? ESZ : DIM, C = which ? DIM : ESZ;
  const float* src = (which ? values : keys) + (size_t)e*DIM*ESZ;
  bf16* dst = (which ? vT : kT) + (size_t)e*DIM*ESZ;
  const int ctiles = C/32;
  const int r0 = (blockIdx.x / ctiles)*32, c0 = (blockIdx.x % ctiles)*32;
  const int tx = threadIdx.x & 31, ty = threadIdx.x >> 5;
#pragma unroll
  for (int i=0;i<4;i++){ int r = ty + i*8; tile[r][tx] = src[(size_t)(r0+r)*C + c0 + tx]; }
  __syncthreads();
#pragma unroll
  for (int i=0;i<4;i++){ int r = ty + i*8; dst[(size_t)(c0+r)*R + r0 + tx] = __float2bfloat16(tile[tx][r]); }
}

// ---------------- per-block histogram (LDS atomics only) --------------------
__global__ __launch_bounds__(256) void k_hist(const int* __restrict__ sel_idx,
    int* __restrict__ block_hist)
{
  __shared__ int h[NEXP];
  if (threadIdx.x < NEXP) h[threadIdx.x]=0;
  __syncthreads();
  atomicAdd(&h[sel_idx[blockIdx.x*256 + threadIdx.x]], 1);
  __syncthreads();
  if (threadIdx.x < NEXP) block_hist[blockIdx.x*NEXP + threadIdx.x] = h[threadIdx.x];
}

// ------- totals -> padded segments + tile map + per-block bases -------------
__global__ void k_meta(const int* __restrict__ block_hist,
    int* __restrict__ tile_expert, int* __restrict__ tile_rowstart,
    int* __restrict__ tile_segend, int* __restrict__ block_base)
{
  __shared__ int cnt[NEXP], seg[NEXP];
  const int tid = threadIdx.x;
  if (tid < NEXP){
    int s=0;
    for (int b=0;b<NBLK;b++) s += block_hist[b*NEXP + tid];
    cnt[tid]=s;
  }
  __syncthreads();
  if (tid==0){
    int off=0, tc=0;
    for (int e=0;e<NEXP;e++){
      seg[e]=off;
      int c = cnt[e];
      int nt = (c + BM - 1)/BM;
      for (int i=0;i<nt;i++){
        tile_expert[tc]=e; tile_rowstart[tc]=off+i*BM; tile_segend[tc]=off+c; tc++;
      }
      off += nt*BM;            // 128-padded segments: tiles never overlap experts
    }
    for (; tc<MAXTILES; tc++) tile_expert[tc]=-1;
  }
  __syncthreads();
  if (tid < NEXP){
    int s = seg[tid];
    for (int b=0;b<NBLK;b++){ block_base[b*NEXP + tid] = s; s += block_hist[b*NEXP + tid]; }
  }
}

// ------- deterministic scatter: ballot rank + wave prefix, no global atomics
__global__ __launch_bounds__(256) void k_scatter(const int* __restrict__ sel_idx,
    const float* __restrict__ sel_gate, const int* __restrict__ block_base,
    int* __restrict__ assign_token, float* __restrict__ assign_gate,
    int* __restrict__ inv_rows)
{
  __shared__ int wcnt[4][NEXP];
  const int p = blockIdx.x*256 + threadIdx.x;
  const int wave = threadIdx.x >> 6, lane = threadIdx.x & 63;
  const int e = sel_idx[p];
  const float g = sel_gate[p];
  int rank = 0;
#pragma unroll
  for (int ee=0; ee<NEXP; ee++){
    unsigned long long m = __ballot(e==ee);
    if (lane==0) wcnt[wave][ee] = (int)__popcll(m);
    if (e==ee) rank = (int)__popcll(m & ((1ull<<lane)-1ull));
  }
  __syncthreads();
  int pre = 0;
  for (int w=0; w<wave; w++) pre += wcnt[w][e];
  const int row = block_base[blockIdx.x*NEXP + e] + pre + rank;
  assign_token[row] = p >> 2;
  assign_gate[row]  = g;
  inv_rows[p] = row;
}

// ---------------- fused expert kernel: per 128-row tile ---------------------
// phase 1: h[128][256] = relu(X @ K_e) * gate   (K=1024, BK=64, dbuf)
// phase 2: partial[128][1024] = h @ V_e  via out^T = V^T @ h^T (K=256)
__global__ __launch_bounds__(512) void k_expert(
    const bf16* __restrict__ xb, const bf16* __restrict__ kT,
    const bf16* __restrict__ vT,
    const int* __restrict__ assign_token, const float* __restrict__ assign_gate,
    const int* __restrict__ tile_expert, const int* __restrict__ tile_rowstart,
    const int* __restrict__ tile_segend, bf16* __restrict__ partial)
{
  __shared__ char smem[98304];        // ph1: A 2x16K | B 2x32K ; ph2: h 64K | V 2x16K
  __shared__ int   tokens_s[BM];
  __shared__ float gates_s[BM];

  const int bid = blockIdx.x;
  const int tile = (bid & 7)*34 + (bid >> 3);   // XCD-chunked bijection (272=8*34)
  const int e = tile_expert[tile];
  if (e < 0) return;
  const int row0 = tile_rowstart[tile];
  const int segend = tile_segend[tile];
  const int tid = threadIdx.x, wave = tid>>6, lane = tid&63;

  if (tid < BM){
    int rg = row0 + tid;
    bool vld = rg < segend;
    tokens_s[tid] = vld ? assign_token[rg] : 0;
    gates_s[tid]  = vld ? assign_gate[rg]  : 0.f;
  }
  __syncthreads();

  // ---------------- phase 1 ----------------
  char* As = smem;                  // 2 x 16 KB
  char* Bs = smem + 32768;          // 2 x 32 KB

  const bf16* gA[2]; int loA[2];
#pragma unroll
  for (int i=0;i<2;i++){
    int r = wave*16 + i*8 + (lane>>3);
    int c = (lane&7) ^ (r&7);                  // source-side XOR pre-swizzle
    gA[i] = xb + (size_t)tokens_s[r]*DIM + c*8;
    loA[i] = (wave*2+i)*1024;
  }
  const bf16* gB[4]; int loB[4];
#pragma unroll
  for (int i=0;i<4;i++){
    int col = wave*32 + i*8 + (lane>>3);
    int c = (lane&7) ^ (col&7);
    gB[i] = kT + ((size_t)e*ESZ + col)*DIM + c*8;
    loB[i] = (wave*4+i)*1024;
  }

  f32x4 acc[4][4];
#pragma unroll
  for (int m=0;m<4;m++)
#pragma unroll
    for (int n=0;n<4;n++) acc[m][n] = {0.f,0.f,0.f,0.f};

  const int wr0 = (wave>>2)*64, wc0 = (wave&3)*64;   // 2x4 waves over 128x256

#pragma unroll
  for (int i=0;i<2;i++) gload16(gA[i], As + loA[i]);
#pragma unroll
  for (int i=0;i<4;i++) gload16(gB[i], Bs + loB[i]);
  asm volatile("s_waitcnt vmcnt(0)" ::: "memory");
  __builtin_amdgcn_s_barrier();

  for (int kt=0; kt<16; ++kt){
    const int cur = kt & 1;
    if (kt < 15){
      const int nxt = cur^1;
#pragma unroll
      for (int i=0;i<2;i++) gload16(gA[i] + (kt+1)*BK, As + nxt*16384 + loA[i]);
#pragma unroll
      for (int i=0;i<4;i++) gload16(gB[i] + (kt+1)*BK, Bs + nxt*32768 + loB[i]);
    }
    const char* Ab = As + cur*16384;
    const char* Bb = Bs + cur*32768;
#pragma unroll
    for (int kk=0;kk<2;kk++){
      bf16x8 af[4], bfr[4];
#pragma unroll
      for (int m=0;m<4;m++){
        int row = wr0 + m*16 + (lane&15);
        int kb  = kk*64 + (lane>>4)*16;
        af[m] = *(const bf16x8*)(Ab + row*128 + (kb ^ ((row&7)<<4)));
      }
#pragma unroll
      for (int n=0;n<4;n++){
        int col = wc0 + n*16 + (lane&15);
        int kb  = kk*64 + (lane>>4)*16;
        bfr[n] = *(const bf16x8*)(Bb + col*128 + (kb ^ ((col&7)<<4)));
      }
#pragma unroll
      for (int m=0;m<4;m++)
#pragma unroll
        for (int n=0;n<4;n++)
          acc[m][n] = __builtin_amdgcn_mfma_f32_16x16x32_bf16(af[m], bfr[n], acc[m][n], 0,0,0);
    }
    asm volatile("s_waitcnt vmcnt(0)" ::: "memory");
    __builtin_amdgcn_s_barrier();
  }

  // ------------- transition: stage V step0, spill h -> LDS ------------------
  char* h_s = smem;                 // 64 KB: [row 128][k 256] bf16, XOR-swizzled
  char* Vs  = smem + 65536;         // 2 x 16 KB
  const bf16* gV[2]; int loV[2];
#pragma unroll
  for (int i=0;i<2;i++){
    int vr = wave*16 + i*8 + (lane>>3);
    int c  = (lane&7) ^ (vr&7);
    gV[i] = vT + ((size_t)e*DIM + vr)*ESZ + c*8;
    loV[i] = (wave*2+i)*1024;
  }
#pragma unroll
  for (int i=0;i<2;i++) gload16(gV[i], Vs + loV[i]);

#pragma unroll
  for (int m=0;m<4;m++)
#pragma unroll
    for (int n=0;n<4;n++){
      int col = wc0 + n*16 + (lane&15);
#pragma unroll
      for (int j=0;j<4;j++){
        int row = wr0 + m*16 + ((lane>>4)<<2) + j;
        float v = fmaxf(acc[m][n][j], 0.f) * gates_s[row];
        *(unsigned short*)(h_s + row*512 + ((col*2) ^ ((row&7)<<4))) = f2bu(v);
      }
    }
  asm volatile("s_waitcnt vmcnt(0) lgkmcnt(0)" ::: "memory");
  __builtin_amdgcn_s_barrier();

  // ---------------- phase 2: out^T = V^T @ h^T ------------------------------
  f32x4 acc2[4][2];
#pragma unroll
  for (int m=0;m<4;m++)
#pragma unroll
    for (int n=0;n<2;n++) acc2[m][n] = {0.f,0.f,0.f,0.f};
  const int qr0 = (wave>>2)*64;     // outdim base within 128-chunk
  const int qc0 = (wave&3)*32;      // token base

  for (int s=0; s<32; ++s){         // 8 outdim-chunks x 4 K-steps
    const int cur = s & 1;
    if (s+1 < 32){
      const int nxt = cur^1;
      const int off = ((s+1)>>2)*32768 + ((s+1)&3)*64;   // elements
#pragma unroll
      for (int i=0;i<2;i++) gload16(gV[i] + off, Vs + nxt*16384 + loV[i]);
    }
    const char* Vb = Vs + cur*16384;
    const int kt = s & 3;
#pragma unroll
    for (int kk=0;kk<2;kk++){
      bf16x8 af[4], bfr[2];
#pragma unroll
      for (int m=0;m<4;m++){
        int vr = qr0 + m*16 + (lane&15);
        int kb = kk*64 + (lane>>4)*16;
        af[m] = *(const bf16x8*)(Vb + vr*128 + (kb ^ ((vr&7)<<4)));
      }
#pragma unroll
      for (int n=0;n<2;n++){
        int tok = qc0 + n*16 + (lane&15);
        int hb  = kt*128 + kk*64 + (lane>>4)*16;
        bfr[n] = *(const bf16x8*)(h_s + tok*512 + (hb ^ ((tok&7)<<4)));
      }
#pragma unroll
      for (int m=0;m<4;m++)
#pragma unroll
        for (int n=0;n<2;n++)
          acc2[m][n] = __builtin_amdgcn_mfma_f32_16x16x32_bf16(af[m], bfr[n], acc2[m][n], 0,0,0);
    }
    if (kt == 3){
      const int chunk = s >> 2;
#pragma unroll
      for (int m=0;m<4;m++)
#pragma unroll
        for (int n=0;n<2;n++){
          int tok = qc0 + n*16 + (lane&15);
          int od  = chunk*128 + qr0 + m*16 + ((lane>>4)<<2);
          ushort4 o;
          o.x = f2bu(acc2[m][n][0]); o.y = f2bu(acc2[m][n][1]);
          o.z = f2bu(acc2[m][n][2]); o.w = f2bu(acc2[m][n][3]);
          *(ushort4*)((unsigned short*)partial + (size_t)(row0+tok)*DIM + od) = o;
          acc2[m][n] = {0.f,0.f,0.f,0.f};
        }
    }
    asm volatile("s_waitcnt vmcnt(0)" ::: "memory");
    __builtin_amdgcn_s_barrier();
  }
}

// -------- reduce: out[t] = sum_k partial[inv_rows[t,k]] ---------------------
__global__ __launch_bounds__(256) void k_reduce(const bf16* __restrict__ partial,
    const int* __restrict__ inv_rows, float* __restrict__ out)
{
  const int t = blockIdx.x;
  const int c0 = threadIdx.x * 4;
  int rows[TOPK];
#pragma unroll
  for (int k=0;k<TOPK;k++) rows[k] = inv_rows[t*TOPK+k];
  float a0=0.f,a1=0.f,a2=0.f,a3=0.f;
#pragma unroll
  for (int k=0;k<TOPK;k++){
    ushort4 v = *(const ushort4*)((const unsigned short*)partial + (size_t)rows[k]*DIM + c0);
    a0 += bu2f(v.x); a1 += bu2f(v.y); a2 += bu2f(v.z); a3 += bu2f(v.w);
  }
  float4 o = {a0,a1,a2,a3};
  *(float4*)(out + (size_t)t*DIM + c0) = o;
}

// ---------------------------------------------------------------------------
extern "C" void kernel_launch(void* const* d_in, const int* in_sizes, int n_in,
                              void* d_out, int out_size, void* d_ws, size_t ws_size,
                              hipStream_t stream)
{
  const float* x      = (const float*)d_in[0];
  const float* wg     = (const float*)d_in[1];
  const float* keys   = (const float*)d_in[2];
  const float* values = (const float*)d_in[3];
  float* out = (float*)d_out;

  char* ws = (char*)d_ws;
  size_t off = 0;
  bf16* vT   = (bf16*)(ws+off); off += (size_t)NEXP*DIM*ESZ*2;   // 8.4 MB
  bf16* kT   = (bf16*)(ws+off); off += (size_t)NEXP*ESZ*DIM*2;   // 8.4 MB
  bf16* xb   = (bf16*)(ws+off); off += (size_t)T_TOK*DIM*2;      // 16.8 MB
  int*   sel_idx      = (int*)  (ws+off); off += (size_t)NPAIR*4;
  float* sel_gate     = (float*)(ws+off); off += (size_t)NPAIR*4;
  int*   assign_token = (int*)  (ws+off); off += (size_t)MAXROWS*4;
  float* assign_gate  = (float*)(ws+off); off += (size_t)MAXROWS*4;
  int*   inv_rows     = (int*)  (ws+off); off += (size_t)NPAIR*4;
  int*   block_hist   = (int*)  (ws+off); off += (size_t)NBLK*NEXP*4;
  int*   block_base   = (int*)  (ws+off); off += (size_t)NBLK*NEXP*4;
  int*   tile_expert  = (int*)  (ws+off); off += 4096;
  int*   tile_rowstart= (int*)  (ws+off); off += 4096;
  int*   tile_segend  = (int*)  (ws+off); off += 4096;
  bf16* partial = (bf16*)(ws+off); off += (size_t)MAXROWS*DIM*2; // 71.3 MB

  k_gate<<<T_TOK/4, 256, 0, stream>>>(x, wg, xb, sel_idx, sel_gate);
  k_transpose2<<<dim3(256, NEXP*2), 256, 0, stream>>>(keys, values, kT, vT);
  k_hist<<<NBLK, 256, 0, stream>>>(sel_idx, block_hist);
  k_meta<<<1, 256, 0, stream>>>(block_hist, tile_expert, tile_rowstart, tile_segend, block_base);
  k_scatter<<<NBLK, 256, 0, stream>>>(sel_idx, sel_gate, block_base, assign_token,
      assign_gate, inv_rows);
  k_expert<<<MAXTILES, 512, 0, stream>>>(xb, kT, vT, assign_token, assign_gate,
      tile_expert, tile_rowstart, tile_segend, partial);
  k_reduce<<<T_TOK, 256, 0, stream>>>(partial, inv_rows, out);
}

// Round 7
// 168.739 us; speedup vs baseline: 1.1992x; 1.1992x over previous
//
#include <hip/hip_runtime.h>
#include <hip/hip_bf16.h>
#include <stdint.h>

#define T_TOK 8192
#define DIM   1024
#define NEXP  16
#define ESZ   256
#define TOPK  4
#define BM    128
#define BK    64
#define NPAIR (T_TOK*TOPK)                 // 32768
#define NGB   (T_TOK/4)                    // 2048 gate blocks (4 tokens each)
#define NBLK  128                          // scatter blocks (256 pairs each)
#define MAXROWS (T_TOK*TOPK + NEXP*BM)     // 34816 padded assignment rows
#define MAXTILES (T_TOK*TOPK/BM + NEXP)    // 272

typedef __hip_bfloat16 bf16;
typedef short bf16x8 __attribute__((ext_vector_type(8)));
typedef float f32x4 __attribute__((ext_vector_type(4)));

__device__ __forceinline__ unsigned short f2bu(float f){
  __hip_bfloat16 b = __float2bfloat16(f);
  return *reinterpret_cast<unsigned short*>(&b);
}
__device__ __forceinline__ float bu2f(unsigned short u){
  __hip_bfloat16 b = *reinterpret_cast<__hip_bfloat16*>(&u);
  return __bfloat162float(b);
}

__device__ __forceinline__ void gload16(const void* g, void* l){
  __builtin_amdgcn_global_load_lds((const __attribute__((address_space(1))) void*)g,
                                   (__attribute__((address_space(3))) void*)l, 16, 0, 0);
}

// ------- gating: logits -> sigmoid -> top4, fused x->bf16 + block hist ------
__global__ __launch_bounds__(256) void k_gate(const float* __restrict__ x,
    const float* __restrict__ wg, bf16* __restrict__ xb,
    int* __restrict__ sel_idx, float* __restrict__ sel_gate,
    int* __restrict__ block_hist)
{
  __shared__ int h[NEXP];
  if (threadIdx.x < NEXP) h[threadIdx.x] = 0;
  __syncthreads();

  const int wave = threadIdx.x >> 6, lane = threadIdx.x & 63;
  const int t = blockIdx.x*4 + wave;
  const float* xr = x + (size_t)t*DIM;
  float4 xv[4];
#pragma unroll
  for (int c=0;c<4;c++) xv[c] = *(const float4*)(xr + c*256 + lane*4);
#pragma unroll
  for (int c=0;c<4;c++){
    ushort4 o; o.x=f2bu(xv[c].x); o.y=f2bu(xv[c].y); o.z=f2bu(xv[c].z); o.w=f2bu(xv[c].w);
    *(ushort4*)((unsigned short*)xb + (size_t)t*DIM + c*256 + lane*4) = o;
  }
  float sg[NEXP];
#pragma unroll
  for (int e=0;e<NEXP;e++){
    const float* wr = wg + e*DIM;
    float p = 0.f;
#pragma unroll
    for (int c=0;c<4;c++){
      float4 w = *(const float4*)(wr + c*256 + lane*4);
      p += xv[c].x*w.x + xv[c].y*w.y + xv[c].z*w.z + xv[c].w*w.w;
    }
#pragma unroll
    for (int s=1;s<64;s<<=1) p += __shfl_xor(p, s);
    sg[e] = 1.f/(1.f + expf(-p));
  }
  if (lane==0){
    unsigned chosen = 0;
#pragma unroll
    for (int k=0;k<TOPK;k++){
      float best=-1.f; int bi=0;
#pragma unroll
      for (int e=0;e<NEXP;e++){
        float v = ((chosen>>e)&1u) ? -2.f : sg[e];
        if (v>best){best=v;bi=e;}
      }
      chosen |= 1u<<bi;
      sel_idx[t*TOPK+k]=bi; sel_gate[t*TOPK+k]=best;
      atomicAdd(&h[bi], 1);
    }
  }
  __syncthreads();
  if (threadIdx.x < NEXP) block_hist[blockIdx.x*NEXP + threadIdx.x] = h[threadIdx.x];
}

// ------- merged fp32->bf16 transposes: keys (z<16) and values (z>=16) -------
__global__ __launch_bounds__(256) void k_transpose2(const float* __restrict__ keys,
    const float* __restrict__ values, bf16* __restrict__ kT, bf16* __restrict__ vT)
{
  __shared__ float tile[32][33];
  const int which = blockIdx.y >> 4, e = blockIdx.y & 15;
  const int R = which ? ESZ : DIM, C = which ? DIM : ESZ;
  const float* src = (which ? values : keys) + (size_t)e*DIM*ESZ;
  bf16* dst = (which ? vT : kT) + (size_t)e*DIM*ESZ;
  const int ctiles = C/32;
  const int r0 = (blockIdx.x / ctiles)*32, c0 = (blockIdx.x % ctiles)*32;
  const int tx = threadIdx.x & 31, ty = threadIdx.x >> 5;
#pragma unroll
  for (int i=0;i<4;i++){ int r = ty + i*8; tile[r][tx] = src[(size_t)(r0+r)*C + c0 + tx]; }
  __syncthreads();
#pragma unroll
  for (int i=0;i<4;i++){ int r = ty + i*8; dst[(size_t)(c0+r)*R + r0 + tx] = __float2bfloat16(tile[tx][r]); }
}

// ------- totals -> padded segments + tile map + per-scatter-block bases -----
__global__ void k_meta(const int* __restrict__ gh,
    int* __restrict__ tile_expert, int* __restrict__ tile_rowstart,
    int* __restrict__ tile_segend, int* __restrict__ block_base)
{
  __shared__ int sbc[NBLK][NEXP];     // per-scatter-block counts (8 KB)
  __shared__ int cnt[NEXP], seg[NEXP];
  const int tid = threadIdx.x;
  for (int cell = tid; cell < NBLK*NEXP; cell += 256){
    int sb = cell >> 4, e = cell & 15;
    int s = 0;
#pragma unroll
    for (int g=0; g<16; ++g) s += gh[(sb*16+g)*NEXP + e];
    sbc[sb][e] = s;
  }
  __syncthreads();
  if (tid < NEXP){
    int s=0;
    for (int sb=0; sb<NBLK; sb++) s += sbc[sb][tid];
    cnt[tid]=s;
  }
  __syncthreads();
  if (tid==0){
    int off=0, tc=0;
    for (int e=0;e<NEXP;e++){
      seg[e]=off;
      int c = cnt[e];
      int nt = (c + BM - 1)/BM;
      for (int i=0;i<nt;i++){
        tile_expert[tc]=e; tile_rowstart[tc]=off+i*BM; tile_segend[tc]=off+c; tc++;
      }
      off += nt*BM;            // 128-padded segments: tiles never overlap experts
    }
    for (; tc<MAXTILES; tc++) tile_expert[tc]=-1;
  }
  __syncthreads();
  if (tid < NEXP){
    int s = seg[tid];
    for (int sb=0; sb<NBLK; sb++){ block_base[sb*NEXP + tid] = s; s += sbc[sb][tid]; }
  }
}

// ------- deterministic scatter: ballot rank + wave prefix, no global atomics
__global__ __launch_bounds__(256) void k_scatter(const int* __restrict__ sel_idx,
    const float* __restrict__ sel_gate, const int* __restrict__ block_base,
    int* __restrict__ assign_token, float* __restrict__ assign_gate,
    int* __restrict__ inv_rows)
{
  __shared__ int wcnt[4][NEXP];
  const int p = blockIdx.x*256 + threadIdx.x;
  const int wave = threadIdx.x >> 6, lane = threadIdx.x & 63;
  const int e = sel_idx[p];
  const float g = sel_gate[p];
  int rank = 0;
#pragma unroll
  for (int ee=0; ee<NEXP; ee++){
    unsigned long long m = __ballot(e==ee);
    if (lane==0) wcnt[wave][ee] = (int)__popcll(m);
    if (e==ee) rank = (int)__popcll(m & ((1ull<<lane)-1ull));
  }
  __syncthreads();
  int pre = 0;
  for (int w=0; w<wave; w++) pre += wcnt[w][e];
  const int row = block_base[blockIdx.x*NEXP + e] + pre + rank;
  assign_token[row] = p >> 2;
  assign_gate[row]  = g;
  inv_rows[p] = row;
}

// ---------------- GEMM1: h = bf16( relu(Xg @ keys_e) * gate ) ---------------
// dbuf K-loop, manual 2-step unroll (static buffer bases), hoisted LDS offsets,
// pointer-bump global staging. Raw s_barrier + vmcnt(0) after compute.
__global__ __launch_bounds__(256) void k_gemm1(
    const bf16* __restrict__ xb, const bf16* __restrict__ kT,
    const int* __restrict__ assign_token, const float* __restrict__ assign_gate,
    const int* __restrict__ tile_expert, const int* __restrict__ tile_rowstart,
    const int* __restrict__ tile_segend, bf16* __restrict__ h)
{
  __shared__ char smem[65536];         // A0 | A1 | B0 | B1, 16 KB each
  __shared__ int   tokens_s[BM];
  __shared__ float gates_s[BM];

  const int nb = blockIdx.x, tile = blockIdx.y;
  const int e = tile_expert[tile];
  if (e < 0) return;
  const int row0 = tile_rowstart[tile];
  const int segend = tile_segend[tile];
  const int tid = threadIdx.x, wave = tid>>6, lane = tid&63;

  if (tid < BM){
    int rg = row0 + tid;
    bool vld = rg < segend;
    tokens_s[tid] = vld ? assign_token[rg] : 0;
    gates_s[tid]  = vld ? assign_gate[rg] : 0.f;
  }
  __syncthreads();

  const bf16* qA[4]; const bf16* qB[4]; int lo[4];
#pragma unroll
  for (int i=0;i<4;i++){
    int rl = (wave*4+i)*8 + (lane>>3);
    int c  = (lane&7) ^ (rl&7);                 // source-side XOR pre-swizzle
    qA[i] = xb + (size_t)tokens_s[rl]*DIM + c*8;
    qB[i] = kT + ((size_t)e*ESZ + nb*BM + rl)*DIM + c*8;
    lo[i] = (wave*4+i)*1024;
  }

  const int wr0 = (wave>>1)*64, wc0 = (wave&1)*64;
  int offA[2][4], offB[2][4];                   // K-invariant LDS read offsets
#pragma unroll
  for (int kk=0;kk<2;kk++){
    int kb = kk*64 + (lane>>4)*16;
#pragma unroll
    for (int m=0;m<4;m++){ int row = wr0 + m*16 + (lane&15); offA[kk][m] = row*128 + (kb ^ ((row&7)<<4)); }
#pragma unroll
    for (int n=0;n<4;n++){ int col = wc0 + n*16 + (lane&15); offB[kk][n] = col*128 + (kb ^ ((col&7)<<4)); }
  }

  f32x4 acc[4][4];
#pragma unroll
  for (int m=0;m<4;m++)
#pragma unroll
    for (int n=0;n<4;n++) acc[m][n] = {0.f,0.f,0.f,0.f};

  auto compute = [&](const char* Ab, const char* Bb){
#pragma unroll
    for (int kk=0;kk<2;kk++){
      bf16x8 af[4], bfr[4];
#pragma unroll
      for (int m=0;m<4;m++) af[m]  = *(const bf16x8*)(Ab + offA[kk][m]);
#pragma unroll
      for (int n=0;n<4;n++) bfr[n] = *(const bf16x8*)(Bb + offB[kk][n]);
#pragma unroll
      for (int m=0;m<4;m++)
#pragma unroll
        for (int n=0;n<4;n++)
          acc[m][n] = __builtin_amdgcn_mfma_f32_16x16x32_bf16(af[m], bfr[n], acc[m][n], 0,0,0);
    }
  };

  // prologue: kt=0 -> buf0
#pragma unroll
  for (int i=0;i<4;i++){ gload16(qA[i], smem+lo[i]); gload16(qB[i], smem+32768+lo[i]); qA[i]+=BK; qB[i]+=BK; }
  asm volatile("s_waitcnt vmcnt(0)" ::: "memory");
  __builtin_amdgcn_s_barrier();

  for (int kt=0; kt<16; kt+=2){
    // prefetch kt+1 -> buf1 (kt+1 <= 15 always)
#pragma unroll
    for (int i=0;i<4;i++){ gload16(qA[i], smem+16384+lo[i]); gload16(qB[i], smem+49152+lo[i]); qA[i]+=BK; qB[i]+=BK; }
    compute(smem, smem+32768);
    asm volatile("s_waitcnt vmcnt(0)" ::: "memory");
    __builtin_amdgcn_s_barrier();
    // prefetch kt+2 -> buf0
    if (kt+2 < 16){
#pragma unroll
      for (int i=0;i<4;i++){ gload16(qA[i], smem+lo[i]); gload16(qB[i], smem+32768+lo[i]); qA[i]+=BK; qB[i]+=BK; }
    }
    compute(smem+16384, smem+49152);
    asm volatile("s_waitcnt vmcnt(0)" ::: "memory");
    __builtin_amdgcn_s_barrier();
  }

#pragma unroll
  for (int m=0;m<4;m++)
#pragma unroll
    for (int n=0;n<4;n++){
      int col = wc0 + n*16 + (lane&15);
#pragma unroll
      for (int j=0;j<4;j++){
        int rloc = wr0 + m*16 + ((lane>>4)<<2) + j;
        float v = fmaxf(acc[m][n][j], 0.f) * gates_s[rloc];
        h[(size_t)(row0 + rloc)*ESZ + nb*BM + col] = __float2bfloat16(v);
      }
    }
}

// -------- GEMM2: partial[row] = bf16( h[row] @ values_e )  (no atomics) -----
__global__ __launch_bounds__(256) void k_gemm2(
    const bf16* __restrict__ h, const bf16* __restrict__ vT,
    const int* __restrict__ tile_expert, const int* __restrict__ tile_rowstart,
    bf16* __restrict__ partial)
{
  __shared__ char smem[65536];

  const int nb = blockIdx.x, tile = blockIdx.y;
  const int e = tile_expert[tile];
  if (e < 0) return;
  const int row0 = tile_rowstart[tile];
  const int tid = threadIdx.x, wave = tid>>6, lane = tid&63;

  const bf16* qA[4]; const bf16* qB[4]; int lo[4];
#pragma unroll
  for (int i=0;i<4;i++){
    int rl = (wave*4+i)*8 + (lane>>3);
    int c  = (lane&7) ^ (rl&7);
    qA[i] = h + (size_t)(row0 + rl)*ESZ + c*8;
    qB[i] = vT + ((size_t)e*DIM + nb*BM + rl)*ESZ + c*8;
    lo[i] = (wave*4+i)*1024;
  }

  const int wr0 = (wave>>1)*64, wc0 = (wave&1)*64;
  int offA[2][4], offB[2][4];
#pragma unroll
  for (int kk=0;kk<2;kk++){
    int kb = kk*64 + (lane>>4)*16;
#pragma unroll
    for (int m=0;m<4;m++){ int row = wr0 + m*16 + (lane&15); offA[kk][m] = row*128 + (kb ^ ((row&7)<<4)); }
#pragma unroll
    for (int n=0;n<4;n++){ int col = wc0 + n*16 + (lane&15); offB[kk][n] = col*128 + (kb ^ ((col&7)<<4)); }
  }

  f32x4 acc[4][4];
#pragma unroll
  for (int m=0;m<4;m++)
#pragma unroll
    for (int n=0;n<4;n++) acc[m][n] = {0.f,0.f,0.f,0.f};

  auto compute = [&](const char* Ab, const char* Bb){
#pragma unroll
    for (int kk=0;kk<2;kk++){
      bf16x8 af[4], bfr[4];
#pragma unroll
      for (int m=0;m<4;m++) af[m]  = *(const bf16x8*)(Ab + offA[kk][m]);
#pragma unroll
      for (int n=0;n<4;n++) bfr[n] = *(const bf16x8*)(Bb + offB[kk][n]);
#pragma unroll
      for (int m=0;m<4;m++)
#pragma unroll
        for (int n=0;n<4;n++)
          acc[m][n] = __builtin_amdgcn_mfma_f32_16x16x32_bf16(af[m], bfr[n], acc[m][n], 0,0,0);
    }
  };

#pragma unroll
  for (int i=0;i<4;i++){ gload16(qA[i], smem+lo[i]); gload16(qB[i], smem+32768+lo[i]); qA[i]+=BK; qB[i]+=BK; }
  asm volatile("s_waitcnt vmcnt(0)" ::: "memory");
  __builtin_amdgcn_s_barrier();

  for (int kt=0; kt<4; kt+=2){
#pragma unroll
    for (int i=0;i<4;i++){ gload16(qA[i], smem+16384+lo[i]); gload16(qB[i], smem+49152+lo[i]); qA[i]+=BK; qB[i]+=BK; }
    compute(smem, smem+32768);
    asm volatile("s_waitcnt vmcnt(0)" ::: "memory");
    __builtin_amdgcn_s_barrier();
    if (kt+2 < 4){
#pragma unroll
      for (int i=0;i<4;i++){ gload16(qA[i], smem+lo[i]); gload16(qB[i], smem+32768+lo[i]); qA[i]+=BK; qB[i]+=BK; }
    }
    compute(smem+16384, smem+49152);
    asm volatile("s_waitcnt vmcnt(0)" ::: "memory");
    __builtin_amdgcn_s_barrier();
  }

#pragma unroll
  for (int m=0;m<4;m++)
#pragma unroll
    for (int n=0;n<4;n++){
      int col = wc0 + n*16 + (lane&15);
#pragma unroll
      for (int j=0;j<4;j++){
        int rloc = wr0 + m*16 + ((lane>>4)<<2) + j;
        partial[(size_t)(row0 + rloc)*DIM + nb*BM + col] = __float2bfloat16(acc[m][n][j]);
      }
    }
}

// -------- reduce: out[t] = sum_k partial[inv_rows[t,k]] ---------------------
__global__ __launch_bounds__(256) void k_reduce(const bf16* __restrict__ partial,
    const int* __restrict__ inv_rows, float* __restrict__ out)
{
  const int t = blockIdx.x;
  const int c0 = threadIdx.x * 4;
  int rows[TOPK];
#pragma unroll
  for (int k=0;k<TOPK;k++) rows[k] = inv_rows[t*TOPK+k];
  float a0=0.f,a1=0.f,a2=0.f,a3=0.f;
#pragma unroll
  for (int k=0;k<TOPK;k++){
    ushort4 v = *(const ushort4*)((const unsigned short*)partial + (size_t)rows[k]*DIM + c0);
    a0 += bu2f(v.x); a1 += bu2f(v.y); a2 += bu2f(v.z); a3 += bu2f(v.w);
  }
  float4 o = {a0,a1,a2,a3};
  *(float4*)(out + (size_t)t*DIM + c0) = o;
}

// ---------------------------------------------------------------------------
extern "C" void kernel_launch(void* const* d_in, const int* in_sizes, int n_in,
                              void* d_out, int out_size, void* d_ws, size_t ws_size,
                              hipStream_t stream)
{
  const float* x      = (const float*)d_in[0];
  const float* wg     = (const float*)d_in[1];
  const float* keys   = (const float*)d_in[2];
  const float* values = (const float*)d_in[3];
  float* out = (float*)d_out;

  char* ws = (char*)d_ws;
  size_t off = 0;
  bf16* vT   = (bf16*)(ws+off); off += (size_t)NEXP*DIM*ESZ*2;   // 8.4 MB
  bf16* hbuf = (bf16*)(ws+off); off += (size_t)MAXROWS*ESZ*2;    // 17.8 MB
  int*   sel_idx      = (int*)  (ws+off); off += (size_t)NPAIR*4;
  float* sel_gate     = (float*)(ws+off); off += (size_t)NPAIR*4;
  int*   assign_token = (int*)  (ws+off); off += (size_t)MAXROWS*4;
  float* assign_gate  = (float*)(ws+off); off += (size_t)MAXROWS*4;
  int*   inv_rows     = (int*)  (ws+off); off += (size_t)NPAIR*4;
  int*   block_hist   = (int*)  (ws+off); off += (size_t)NGB*NEXP*4;   // 131 KB
  int*   block_base   = (int*)  (ws+off); off += (size_t)NBLK*NEXP*4;
  int*   tile_expert  = (int*)  (ws+off); off += 4096;
  int*   tile_rowstart= (int*)  (ws+off); off += 4096;
  int*   tile_segend  = (int*)  (ws+off); off += 4096;
  // partial is live only AFTER gemm1; xb/kT are dead after gemm1 -> alias them
  // into partial's tail to cap total workspace at ~98 MB.
  const size_t PARTIAL_BYTES = (size_t)MAXROWS*DIM*2;            // 71.3 MB
  const size_t XB_BYTES = (size_t)T_TOK*DIM*2;                   // 16.8 MB
  const size_t KT_BYTES = (size_t)NEXP*ESZ*DIM*2;                // 8.4 MB
  bf16* partial = (bf16*)(ws+off); off += PARTIAL_BYTES;
  bf16* xb = (bf16*)((char*)partial + PARTIAL_BYTES - XB_BYTES - KT_BYTES);
  bf16* kT = (bf16*)((char*)partial + PARTIAL_BYTES - KT_BYTES);

  k_gate<<<NGB, 256, 0, stream>>>(x, wg, xb, sel_idx, sel_gate, block_hist);
  k_transpose2<<<dim3(256, NEXP*2), 256, 0, stream>>>(keys, values, kT, vT);
  k_meta<<<1, 256, 0, stream>>>(block_hist, tile_expert, tile_rowstart, tile_segend, block_base);
  k_scatter<<<NBLK, 256, 0, stream>>>(sel_idx, sel_gate, block_base, assign_token,
      assign_gate, inv_rows);
  k_gemm1<<<dim3(ESZ/BM, MAXTILES), 256, 0, stream>>>(xb, kT, assign_token, assign_gate,
      tile_expert, tile_rowstart, tile_segend, hbuf);
  k_gemm2<<<dim3(DIM/BM, MAXTILES), 256, 0, stream>>>(hbuf, vT,
      tile_expert, tile_rowstart, partial);
  k_reduce<<<T_TOK, 256, 0, stream>>>(partial, inv_rows, out);
}

// Round 8
// 162.788 us; speedup vs baseline: 1.2430x; 1.0366x over previous
//
#include <hip/hip_runtime.h>
#include <hip/hip_bf16.h>
#include <stdint.h>

#define T_TOK 8192
#define DIM   1024
#define NEXP  16
#define ESZ   256
#define TOPK  4
#define BM    64                           // tile rows (64 for occupancy)
#define BK    64
#define NPAIR (T_TOK*TOPK)                 // 32768
#define NGB   (T_TOK/4)                    // 2048 gate blocks (4 tokens each)
#define NBLK  128                          // scatter blocks (256 pairs each)
#define MAXROWS (NPAIR + NEXP*BM)          // 33792 padded assignment rows
#define MAXTILES (NPAIR/BM + NEXP)         // 528

typedef __hip_bfloat16 bf16;
typedef short bf16x8 __attribute__((ext_vector_type(8)));
typedef float f32x4 __attribute__((ext_vector_type(4)));

__device__ __forceinline__ unsigned short f2bu(float f){
  __hip_bfloat16 b = __float2bfloat16(f);
  return *reinterpret_cast<unsigned short*>(&b);
}
__device__ __forceinline__ float bu2f(unsigned short u){
  __hip_bfloat16 b = *reinterpret_cast<__hip_bfloat16*>(&u);
  return __bfloat162float(b);
}

__device__ __forceinline__ void gload16(const void* g, void* l){
  __builtin_amdgcn_global_load_lds((const __attribute__((address_space(1))) void*)g,
                                   (__attribute__((address_space(3))) void*)l, 16, 0, 0);
}

// ------- gating: logits -> sigmoid -> top4, fused x->bf16 + block hist ------
__global__ __launch_bounds__(256) void k_gate(const float* __restrict__ x,
    const float* __restrict__ wg, bf16* __restrict__ xb,
    int* __restrict__ sel_idx, float* __restrict__ sel_gate,
    int* __restrict__ block_hist)
{
  __shared__ int h[NEXP];
  if (threadIdx.x < NEXP) h[threadIdx.x] = 0;
  __syncthreads();

  const int wave = threadIdx.x >> 6, lane = threadIdx.x & 63;
  const int t = blockIdx.x*4 + wave;
  const float* xr = x + (size_t)t*DIM;
  float4 xv[4];
#pragma unroll
  for (int c=0;c<4;c++) xv[c] = *(const float4*)(xr + c*256 + lane*4);
#pragma unroll
  for (int c=0;c<4;c++){
    ushort4 o; o.x=f2bu(xv[c].x); o.y=f2bu(xv[c].y); o.z=f2bu(xv[c].z); o.w=f2bu(xv[c].w);
    *(ushort4*)((unsigned short*)xb + (size_t)t*DIM + c*256 + lane*4) = o;
  }
  float sg[NEXP];
#pragma unroll
  for (int e=0;e<NEXP;e++){
    const float* wr = wg + e*DIM;
    float p = 0.f;
#pragma unroll
    for (int c=0;c<4;c++){
      float4 w = *(const float4*)(wr + c*256 + lane*4);
      p += xv[c].x*w.x + xv[c].y*w.y + xv[c].z*w.z + xv[c].w*w.w;
    }
#pragma unroll
    for (int s=1;s<64;s<<=1) p += __shfl_xor(p, s);
    sg[e] = 1.f/(1.f + expf(-p));
  }
  if (lane==0){
    unsigned chosen = 0;
#pragma unroll
    for (int k=0;k<TOPK;k++){
      float best=-1.f; int bi=0;
#pragma unroll
      for (int e=0;e<NEXP;e++){
        float v = ((chosen>>e)&1u) ? -2.f : sg[e];
        if (v>best){best=v;bi=e;}
      }
      chosen |= 1u<<bi;
      sel_idx[t*TOPK+k]=bi; sel_gate[t*TOPK+k]=best;
      atomicAdd(&h[bi], 1);
    }
  }
  __syncthreads();
  if (threadIdx.x < NEXP) block_hist[blockIdx.x*NEXP + threadIdx.x] = h[threadIdx.x];
}

// ------- merged fp32->bf16 transposes: keys (z<16) and values (z>=16) -------
__global__ __launch_bounds__(256) void k_transpose2(const float* __restrict__ keys,
    const float* __restrict__ values, bf16* __restrict__ kT, bf16* __restrict__ vT)
{
  __shared__ float tile[32][33];
  const int which = blockIdx.y >> 4, e = blockIdx.y & 15;
  const int R = which ? ESZ : DIM, C = which ? DIM : ESZ;
  const float* src = (which ? values : keys) + (size_t)e*DIM*ESZ;
  bf16* dst = (which ? vT : kT) + (size_t)e*DIM*ESZ;
  const int ctiles = C/32;
  const int r0 = (blockIdx.x / ctiles)*32, c0 = (blockIdx.x % ctiles)*32;
  const int tx = threadIdx.x & 31, ty = threadIdx.x >> 5;
#pragma unroll
  for (int i=0;i<4;i++){ int r = ty + i*8; tile[r][tx] = src[(size_t)(r0+r)*C + c0 + tx]; }
  __syncthreads();
#pragma unroll
  for (int i=0;i<4;i++){ int r = ty + i*8; dst[(size_t)(c0+r)*R + r0 + tx] = __float2bfloat16(tile[tx][r]); }
}

// ------- totals -> 64-padded segments + tile map + per-scatter-block bases --
__global__ void k_meta(const int* __restrict__ gh,
    int* __restrict__ tile_expert, int* __restrict__ tile_rowstart,
    int* __restrict__ tile_segend, int* __restrict__ block_base)
{
  __shared__ int sbc[NBLK][NEXP];     // per-scatter-block counts (8 KB)
  __shared__ int cnt[NEXP], seg[NEXP];
  const int tid = threadIdx.x;
  for (int cell = tid; cell < NBLK*NEXP; cell += 256){
    int sb = cell >> 4, e = cell & 15;
    int s = 0;
#pragma unroll
    for (int g=0; g<16; ++g) s += gh[(sb*16+g)*NEXP + e];
    sbc[sb][e] = s;
  }
  __syncthreads();
  if (tid < NEXP){
    int s=0;
    for (int sb=0; sb<NBLK; sb++) s += sbc[sb][tid];
    cnt[tid]=s;
  }
  __syncthreads();
  if (tid==0){
    int off=0, tc=0;
    for (int e=0;e<NEXP;e++){
      seg[e]=off;
      int c = cnt[e];
      int nt = (c + BM - 1)/BM;
      for (int i=0;i<nt;i++){
        tile_expert[tc]=e; tile_rowstart[tc]=off+i*BM; tile_segend[tc]=off+c; tc++;
      }
      off += nt*BM;            // 64-padded segments: tiles never overlap experts
    }
    for (; tc<MAXTILES; tc++) tile_expert[tc]=-1;
  }
  __syncthreads();
  if (tid < NEXP){
    int s = seg[tid];
    for (int sb=0; sb<NBLK; sb++){ block_base[sb*NEXP + tid] = s; s += sbc[sb][tid]; }
  }
}

// ------- deterministic scatter: ballot rank + wave prefix, no global atomics
__global__ __launch_bounds__(256) void k_scatter(const int* __restrict__ sel_idx,
    const float* __restrict__ sel_gate, const int* __restrict__ block_base,
    int* __restrict__ assign_token, float* __restrict__ assign_gate,
    int* __restrict__ inv_rows)
{
  __shared__ int wcnt[4][NEXP];
  const int p = blockIdx.x*256 + threadIdx.x;
  const int wave = threadIdx.x >> 6, lane = threadIdx.x & 63;
  const int e = sel_idx[p];
  const float g = sel_gate[p];
  int rank = 0;
#pragma unroll
  for (int ee=0; ee<NEXP; ee++){
    unsigned long long m = __ballot(e==ee);
    if (lane==0) wcnt[wave][ee] = (int)__popcll(m);
    if (e==ee) rank = (int)__popcll(m & ((1ull<<lane)-1ull));
  }
  __syncthreads();
  int pre = 0;
  for (int w=0; w<wave; w++) pre += wcnt[w][e];
  const int row = block_base[blockIdx.x*NEXP + e] + pre + rank;
  assign_token[row] = p >> 2;
  assign_gate[row]  = g;
  inv_rows[p] = row;
}

// ---------------- GEMM1: h = bf16( relu(Xg @ keys_e) * gate ) ---------------
// 64x128 tile, 4 waves of 32x64, LDS 48KB dbuf -> 3 blocks/CU, 1056 blocks.
__global__ __launch_bounds__(256) void k_gemm1(
    const bf16* __restrict__ xb, const bf16* __restrict__ kT,
    const int* __restrict__ assign_token, const float* __restrict__ assign_gate,
    const int* __restrict__ tile_expert, const int* __restrict__ tile_rowstart,
    const int* __restrict__ tile_segend, bf16* __restrict__ h)
{
  __shared__ char smem[49152];   // A0(8K) A1(8K) B0(16K) B1(16K)
  __shared__ int   tokens_s[BM];
  __shared__ float gates_s[BM];

  const int nb = blockIdx.x, tile = blockIdx.y;
  const int e = tile_expert[tile];
  if (e < 0) return;
  const int row0 = tile_rowstart[tile];
  const int segend = tile_segend[tile];
  const int tid = threadIdx.x, wave = tid>>6, lane = tid&63;

  if (tid < BM){
    int rg = row0 + tid;
    bool vld = rg < segend;
    tokens_s[tid] = vld ? assign_token[rg] : 0;
    gates_s[tid]  = vld ? assign_gate[rg] : 0.f;
  }
  __syncthreads();

  // staging: A = 2 instr-rounds (64 rows), B = 4 rounds (128 cols)
  const bf16* qA[2]; const bf16* qB[4]; int loA[2], loB[4];
#pragma unroll
  for (int i=0;i<2;i++){
    int row = i*32 + wave*8 + (lane>>3);
    int c   = (lane&7) ^ (row&7);               // source-side XOR pre-swizzle
    qA[i] = xb + (size_t)tokens_s[row]*DIM + c*8;
    loA[i] = i*4096 + wave*1024;
  }
#pragma unroll
  for (int i=0;i<4;i++){
    int col = i*32 + wave*8 + (lane>>3);
    int c   = (lane&7) ^ (col&7);
    qB[i] = kT + ((size_t)e*ESZ + nb*128 + col)*DIM + c*8;
    loB[i] = i*4096 + wave*1024;
  }

  const int wr0 = (wave>>1)*32, wc0 = (wave&1)*64;
  int offA[2][2], offB[2][4];                   // K-invariant LDS read offsets
#pragma unroll
  for (int kk=0;kk<2;kk++){
    int kb = kk*64 + (lane>>4)*16;
#pragma unroll
    for (int m=0;m<2;m++){ int row = wr0 + m*16 + (lane&15); offA[kk][m] = row*128 + (kb ^ ((row&7)<<4)); }
#pragma unroll
    for (int n=0;n<4;n++){ int col = wc0 + n*16 + (lane&15); offB[kk][n] = col*128 + (kb ^ ((col&7)<<4)); }
  }

  f32x4 acc[2][4];
#pragma unroll
  for (int m=0;m<2;m++)
#pragma unroll
    for (int n=0;n<4;n++) acc[m][n] = {0.f,0.f,0.f,0.f};

  auto stage = [&](int abase, int bbase){
#pragma unroll
    for (int i=0;i<2;i++){ gload16(qA[i], smem + abase + loA[i]); qA[i]+=BK; }
#pragma unroll
    for (int i=0;i<4;i++){ gload16(qB[i], smem + bbase + loB[i]); qB[i]+=BK; }
  };
  auto compute = [&](const char* Ab, const char* Bb){
#pragma unroll
    for (int kk=0;kk<2;kk++){
      bf16x8 af[2], bfr[4];
#pragma unroll
      for (int m=0;m<2;m++) af[m]  = *(const bf16x8*)(Ab + offA[kk][m]);
#pragma unroll
      for (int n=0;n<4;n++) bfr[n] = *(const bf16x8*)(Bb + offB[kk][n]);
#pragma unroll
      for (int m=0;m<2;m++)
#pragma unroll
        for (int n=0;n<4;n++)
          acc[m][n] = __builtin_amdgcn_mfma_f32_16x16x32_bf16(af[m], bfr[n], acc[m][n], 0,0,0);
    }
  };

  stage(0, 16384);                                   // kt=0 -> buf0
  asm volatile("s_waitcnt vmcnt(0)" ::: "memory");
  __builtin_amdgcn_s_barrier();

  for (int kt=0; kt<16; kt+=2){
    stage(8192, 32768);                              // kt+1 -> buf1
    compute(smem, smem+16384);
    asm volatile("s_waitcnt vmcnt(0)" ::: "memory");
    __builtin_amdgcn_s_barrier();
    if (kt+2 < 16) stage(0, 16384);                  // kt+2 -> buf0
    compute(smem+8192, smem+32768);
    asm volatile("s_waitcnt vmcnt(0)" ::: "memory");
    __builtin_amdgcn_s_barrier();
  }

#pragma unroll
  for (int m=0;m<2;m++)
#pragma unroll
    for (int n=0;n<4;n++){
      int col = wc0 + n*16 + (lane&15);
#pragma unroll
      for (int j=0;j<4;j++){
        int rloc = wr0 + m*16 + ((lane>>4)<<2) + j;
        float v = fmaxf(acc[m][n][j], 0.f) * gates_s[rloc];
        h[(size_t)(row0 + rloc)*ESZ + nb*128 + col] = __float2bfloat16(v);
      }
    }
}

// -------- GEMM2: partial[row] = bf16( h[row] @ values_e )  (no atomics) -----
__global__ __launch_bounds__(256) void k_gemm2(
    const bf16* __restrict__ h, const bf16* __restrict__ vT,
    const int* __restrict__ tile_expert, const int* __restrict__ tile_rowstart,
    bf16* __restrict__ partial)
{
  __shared__ char smem[49152];

  const int nb = blockIdx.x, tile = blockIdx.y;
  const int e = tile_expert[tile];
  if (e < 0) return;
  const int row0 = tile_rowstart[tile];
  const int tid = threadIdx.x, wave = tid>>6, lane = tid&63;

  const bf16* qA[2]; const bf16* qB[4]; int loA[2], loB[4];
#pragma unroll
  for (int i=0;i<2;i++){
    int row = i*32 + wave*8 + (lane>>3);
    int c   = (lane&7) ^ (row&7);
    qA[i] = h + (size_t)(row0 + row)*ESZ + c*8;
    loA[i] = i*4096 + wave*1024;
  }
#pragma unroll
  for (int i=0;i<4;i++){
    int col = i*32 + wave*8 + (lane>>3);
    int c   = (lane&7) ^ (col&7);
    qB[i] = vT + ((size_t)e*DIM + nb*128 + col)*ESZ + c*8;
    loB[i] = i*4096 + wave*1024;
  }

  const int wr0 = (wave>>1)*32, wc0 = (wave&1)*64;
  int offA[2][2], offB[2][4];
#pragma unroll
  for (int kk=0;kk<2;kk++){
    int kb = kk*64 + (lane>>4)*16;
#pragma unroll
    for (int m=0;m<2;m++){ int row = wr0 + m*16 + (lane&15); offA[kk][m] = row*128 + (kb ^ ((row&7)<<4)); }
#pragma unroll
    for (int n=0;n<4;n++){ int col = wc0 + n*16 + (lane&15); offB[kk][n] = col*128 + (kb ^ ((col&7)<<4)); }
  }

  f32x4 acc[2][4];
#pragma unroll
  for (int m=0;m<2;m++)
#pragma unroll
    for (int n=0;n<4;n++) acc[m][n] = {0.f,0.f,0.f,0.f};

  auto stage = [&](int abase, int bbase){
#pragma unroll
    for (int i=0;i<2;i++){ gload16(qA[i], smem + abase + loA[i]); qA[i]+=BK; }
#pragma unroll
    for (int i=0;i<4;i++){ gload16(qB[i], smem + bbase + loB[i]); qB[i]+=BK; }
  };
  auto compute = [&](const char* Ab, const char* Bb){
#pragma unroll
    for (int kk=0;kk<2;kk++){
      bf16x8 af[2], bfr[4];
#pragma unroll
      for (int m=0;m<2;m++) af[m]  = *(const bf16x8*)(Ab + offA[kk][m]);
#pragma unroll
      for (int n=0;n<4;n++) bfr[n] = *(const bf16x8*)(Bb + offB[kk][n]);
#pragma unroll
      for (int m=0;m<2;m++)
#pragma unroll
        for (int n=0;n<4;n++)
          acc[m][n] = __builtin_amdgcn_mfma_f32_16x16x32_bf16(af[m], bfr[n], acc[m][n], 0,0,0);
    }
  };

  stage(0, 16384);
  asm volatile("s_waitcnt vmcnt(0)" ::: "memory");
  __builtin_amdgcn_s_barrier();

  // NT = 4: two unrolled pairs
  stage(8192, 32768);
  compute(smem, smem+16384);
  asm volatile("s_waitcnt vmcnt(0)" ::: "memory");
  __builtin_amdgcn_s_barrier();
  stage(0, 16384);
  compute(smem+8192, smem+32768);
  asm volatile("s_waitcnt vmcnt(0)" ::: "memory");
  __builtin_amdgcn_s_barrier();
  stage(8192, 32768);
  compute(smem, smem+16384);
  asm volatile("s_waitcnt vmcnt(0)" ::: "memory");
  __builtin_amdgcn_s_barrier();
  compute(smem+8192, smem+32768);

#pragma unroll
  for (int m=0;m<2;m++)
#pragma unroll
    for (int n=0;n<4;n++){
      int col = wc0 + n*16 + (lane&15);
#pragma unroll
      for (int j=0;j<4;j++){
        int rloc = wr0 + m*16 + ((lane>>4)<<2) + j;
        partial[(size_t)(row0 + rloc)*DIM + nb*128 + col] = __float2bfloat16(acc[m][n][j]);
      }
    }
}

// -------- reduce: out[t] = sum_k partial[inv_rows[t,k]] ---------------------
__global__ __launch_bounds__(256) void k_reduce(const bf16* __restrict__ partial,
    const int* __restrict__ inv_rows, float* __restrict__ out)
{
  const int t = blockIdx.x;
  const int c0 = threadIdx.x * 4;
  int rows[TOPK];
#pragma unroll
  for (int k=0;k<TOPK;k++) rows[k] = inv_rows[t*TOPK+k];
  float a0=0.f,a1=0.f,a2=0.f,a3=0.f;
#pragma unroll
  for (int k=0;k<TOPK;k++){
    ushort4 v = *(const ushort4*)((const unsigned short*)partial + (size_t)rows[k]*DIM + c0);
    a0 += bu2f(v.x); a1 += bu2f(v.y); a2 += bu2f(v.z); a3 += bu2f(v.w);
  }
  float4 o = {a0,a1,a2,a3};
  *(float4*)(out + (size_t)t*DIM + c0) = o;
}

// ---------------------------------------------------------------------------
extern "C" void kernel_launch(void* const* d_in, const int* in_sizes, int n_in,
                              void* d_out, int out_size, void* d_ws, size_t ws_size,
                              hipStream_t stream)
{
  const float* x      = (const float*)d_in[0];
  const float* wg     = (const float*)d_in[1];
  const float* keys   = (const float*)d_in[2];
  const float* values = (const float*)d_in[3];
  float* out = (float*)d_out;

  char* ws = (char*)d_ws;
  size_t off = 0;
  bf16* vT   = (bf16*)(ws+off); off += (size_t)NEXP*DIM*ESZ*2;   // 8.4 MB
  bf16* hbuf = (bf16*)(ws+off); off += (size_t)MAXROWS*ESZ*2;    // 17.3 MB
  int*   sel_idx      = (int*)  (ws+off); off += (size_t)NPAIR*4;
  float* sel_gate     = (float*)(ws+off); off += (size_t)NPAIR*4;
  int*   assign_token = (int*)  (ws+off); off += (size_t)MAXROWS*4;
  float* assign_gate  = (float*)(ws+off); off += (size_t)MAXROWS*4;
  int*   inv_rows     = (int*)  (ws+off); off += (size_t)NPAIR*4;
  int*   block_hist   = (int*)  (ws+off); off += (size_t)NGB*NEXP*4;   // 131 KB
  int*   block_base   = (int*)  (ws+off); off += (size_t)NBLK*NEXP*4;
  int*   tile_expert  = (int*)  (ws+off); off += 4096;
  int*   tile_rowstart= (int*)  (ws+off); off += 4096;
  int*   tile_segend  = (int*)  (ws+off); off += 4096;
  // partial is live only AFTER gemm1; xb/kT are dead after gemm1 -> alias them
  // into partial's tail.
  const size_t PARTIAL_BYTES = (size_t)MAXROWS*DIM*2;            // 69.2 MB
  const size_t XB_BYTES = (size_t)T_TOK*DIM*2;                   // 16.8 MB
  const size_t KT_BYTES = (size_t)NEXP*ESZ*DIM*2;                // 8.4 MB
  bf16* partial = (bf16*)(ws+off); off += PARTIAL_BYTES;
  bf16* xb = (bf16*)((char*)partial + PARTIAL_BYTES - XB_BYTES - KT_BYTES);
  bf16* kT = (bf16*)((char*)partial + PARTIAL_BYTES - KT_BYTES);

  k_gate<<<NGB, 256, 0, stream>>>(x, wg, xb, sel_idx, sel_gate, block_hist);
  k_transpose2<<<dim3(256, NEXP*2), 256, 0, stream>>>(keys, values, kT, vT);
  k_meta<<<1, 256, 0, stream>>>(block_hist, tile_expert, tile_rowstart, tile_segend, block_base);
  k_scatter<<<NBLK, 256, 0, stream>>>(sel_idx, sel_gate, block_base, assign_token,
      assign_gate, inv_rows);
  k_gemm1<<<dim3(2, MAXTILES), 256, 0, stream>>>(xb, kT, assign_token, assign_gate,
      tile_expert, tile_rowstart, tile_segend, hbuf);
  k_gemm2<<<dim3(8, MAXTILES), 256, 0, stream>>>(hbuf, vT,
      tile_expert, tile_rowstart, partial);
  k_reduce<<<T_TOK, 256, 0, stream>>>(partial, inv_rows, out);
}